// Round 1
// baseline (2692.208 us; speedup 1.0000x reference)
//
#include <hip/hip_runtime.h>

#define N_NODES 100000
#define N_EDGES 3200000
#define IN_DIM  256
#define OUT_DIM 128

#define BM 64
#define BK 32

// ---------------- GEMM: support[M,128] = X[M,256] @ W[256,128] ----------------
// 64x128 tile per block, BK=32, 256 threads, each thread 4 rows x 8 cols.
__global__ __launch_bounds__(256) void gemm_kernel(const float* __restrict__ X,
                                                   const float* __restrict__ W,
                                                   float* __restrict__ S) {
    __shared__ float xs[BM][BK + 1];   // +1 pad: kill bank conflicts on xs[r][k]
    __shared__ float ws[BK][OUT_DIM];  // 16 KB

    const int t    = threadIdx.x;
    const int row0 = blockIdx.x * BM;
    const int tx   = t & 15;   // 16 col-groups
    const int ty   = t >> 4;   // 16 row-groups

    float acc[4][8];
#pragma unroll
    for (int i = 0; i < 4; ++i)
#pragma unroll
        for (int j = 0; j < 8; ++j) acc[i][j] = 0.f;

    for (int k0 = 0; k0 < IN_DIM; k0 += BK) {
        // load X tile: 64 rows x 32 cols = 512 float4, 2 per thread
#pragma unroll
        for (int it = 0; it < 2; ++it) {
            int i  = t + it * 256;
            int r  = i >> 3;         // 8 float4 per row
            int c4 = i & 7;
            int gr = row0 + r;
            float4 v;
            if (gr < N_NODES) {
                v = reinterpret_cast<const float4*>(X + (size_t)gr * IN_DIM + k0)[c4];
            } else {
                v = make_float4(0.f, 0.f, 0.f, 0.f);
            }
            xs[r][c4 * 4 + 0] = v.x;
            xs[r][c4 * 4 + 1] = v.y;
            xs[r][c4 * 4 + 2] = v.z;
            xs[r][c4 * 4 + 3] = v.w;
        }
        // load W tile: 32 rows x 128 cols = 1024 float4, 4 per thread
#pragma unroll
        for (int it = 0; it < 4; ++it) {
            int i  = t + it * 256;
            int r  = i >> 5;         // 32 float4 per row
            int c4 = i & 31;
            float4 v = reinterpret_cast<const float4*>(W + (size_t)(k0 + r) * OUT_DIM)[c4];
            *reinterpret_cast<float4*>(&ws[r][c4 * 4]) = v;
        }
        __syncthreads();

#pragma unroll
        for (int k = 0; k < BK; ++k) {
            float xv[4], wv[8];
#pragma unroll
            for (int i = 0; i < 4; ++i) xv[i] = xs[ty * 4 + i][k];
#pragma unroll
            for (int j = 0; j < 4; ++j) wv[j] = ws[k][tx * 4 + j];          // cols 0..63: 2 lanes/bank -> free
#pragma unroll
            for (int j = 0; j < 4; ++j) wv[4 + j] = ws[k][64 + tx * 4 + j]; // cols 64..127
#pragma unroll
            for (int i = 0; i < 4; ++i)
#pragma unroll
                for (int j = 0; j < 8; ++j) acc[i][j] += xv[i] * wv[j];
        }
        __syncthreads();
    }

    // write 4 rows, two float4 chunks per row (cols tx*4 and 64+tx*4)
#pragma unroll
    for (int i = 0; i < 4; ++i) {
        int gr = row0 + ty * 4 + i;
        if (gr >= N_NODES) break;
        float* orow = S + (size_t)gr * OUT_DIM;
        float4 a = make_float4(acc[i][0], acc[i][1], acc[i][2], acc[i][3]);
        float4 b = make_float4(acc[i][4], acc[i][5], acc[i][6], acc[i][7]);
        reinterpret_cast<float4*>(orow)[tx]      = a;
        reinterpret_cast<float4*>(orow + 64)[tx] = b;
    }
}

// ---------------- init: out[r][c] = bias[c] ----------------
__global__ __launch_bounds__(256) void init_out_kernel(const float* __restrict__ bias,
                                                       float* __restrict__ out) {
    int i = blockIdx.x * 256 + threadIdx.x;       // over 3.2M float4
    float4 b = reinterpret_cast<const float4*>(bias)[i & 31];
    reinterpret_cast<float4*>(out)[i] = b;
}

// ---------------- SpMM scatter: one wave per edge, float2 per lane ----------------
__global__ __launch_bounds__(256) void spmm_atomic_kernel(const int* __restrict__ rows,
                                                          const int* __restrict__ cols,
                                                          const float* __restrict__ vals,
                                                          const float* __restrict__ support,
                                                          float* __restrict__ out) {
    const int wave = (blockIdx.x * 256 + threadIdx.x) >> 6;   // global wave id == edge id
    const int lane = threadIdx.x & 63;
    if (wave >= N_EDGES) return;

    const int   r = rows[wave];
    const int   c = cols[wave];
    const float v = vals[wave];

    const float2 s = reinterpret_cast<const float2*>(support + (size_t)c * OUT_DIM)[lane];
    float* o = out + (size_t)r * OUT_DIM + lane * 2;
    unsafeAtomicAdd(o + 0, v * s.x);
    unsafeAtomicAdd(o + 1, v * s.y);
}

extern "C" void kernel_launch(void* const* d_in, const int* in_sizes, int n_in,
                              void* d_out, int out_size, void* d_ws, size_t ws_size,
                              hipStream_t stream) {
    const float* X    = (const float*)d_in[0];
    const float* W    = (const float*)d_in[1];
    const float* bias = (const float*)d_in[2];
    const int*   rows = (const int*)d_in[3];
    const int*   cols = (const int*)d_in[4];
    const float* vals = (const float*)d_in[5];
    float* out = (float*)d_out;

    float* support = (float*)d_ws;   // 100000*128*4 = 51.2 MB scratch

    // 1) support = X @ W
    int gemm_blocks = (N_NODES + BM - 1) / BM;   // 1563
    hipLaunchKernelGGL(gemm_kernel, dim3(gemm_blocks), dim3(256), 0, stream, X, W, support);

    // 2) out = bias (broadcast)  [12.8M floats = 3.2M float4]
    hipLaunchKernelGGL(init_out_kernel, dim3((N_NODES * (OUT_DIM / 4)) / 256), dim3(256), 0, stream,
                       bias, out);

    // 3) scatter-add edges: 3.2M waves, 4 waves/block -> 800000 blocks
    hipLaunchKernelGGL(spmm_atomic_kernel, dim3(N_EDGES / 4), dim3(256), 0, stream,
                       rows, cols, vals, support, out);
}

// Round 2
// 729.889 us; speedup vs baseline: 3.6885x; 3.6885x over previous
//
#include <hip/hip_runtime.h>

#define N_NODES 100000
#define N_EDGES 3200000
#define IN_DIM  256
#define OUT_DIM 128

#define BM 64
#define BK 32

#define SCAN_BS 1024
#define SCAN_NB ((N_NODES + SCAN_BS - 1) / SCAN_BS)   // 98

// ---------------- GEMM: support[M,128] = X[M,256] @ W[256,128] ----------------
__global__ __launch_bounds__(256) void gemm_kernel(const float* __restrict__ X,
                                                   const float* __restrict__ W,
                                                   float* __restrict__ S) {
    __shared__ float xs[BM][BK + 1];
    __shared__ float ws[BK][OUT_DIM];

    const int t    = threadIdx.x;
    const int row0 = blockIdx.x * BM;
    const int tx   = t & 15;
    const int ty   = t >> 4;

    float acc[4][8];
#pragma unroll
    for (int i = 0; i < 4; ++i)
#pragma unroll
        for (int j = 0; j < 8; ++j) acc[i][j] = 0.f;

    for (int k0 = 0; k0 < IN_DIM; k0 += BK) {
#pragma unroll
        for (int it = 0; it < 2; ++it) {
            int i  = t + it * 256;
            int r  = i >> 3;
            int c4 = i & 7;
            int gr = row0 + r;
            float4 v;
            if (gr < N_NODES) {
                v = reinterpret_cast<const float4*>(X + (size_t)gr * IN_DIM + k0)[c4];
            } else {
                v = make_float4(0.f, 0.f, 0.f, 0.f);
            }
            xs[r][c4 * 4 + 0] = v.x;
            xs[r][c4 * 4 + 1] = v.y;
            xs[r][c4 * 4 + 2] = v.z;
            xs[r][c4 * 4 + 3] = v.w;
        }
#pragma unroll
        for (int it = 0; it < 4; ++it) {
            int i  = t + it * 256;
            int r  = i >> 5;
            int c4 = i & 31;
            float4 v = reinterpret_cast<const float4*>(W + (size_t)(k0 + r) * OUT_DIM)[c4];
            *reinterpret_cast<float4*>(&ws[r][c4 * 4]) = v;
        }
        __syncthreads();

#pragma unroll
        for (int k = 0; k < BK; ++k) {
            float xv[4], wv[8];
#pragma unroll
            for (int i = 0; i < 4; ++i) xv[i] = xs[ty * 4 + i][k];
#pragma unroll
            for (int j = 0; j < 4; ++j) wv[j] = ws[k][tx * 4 + j];
#pragma unroll
            for (int j = 0; j < 4; ++j) wv[4 + j] = ws[k][64 + tx * 4 + j];
#pragma unroll
            for (int i = 0; i < 4; ++i)
#pragma unroll
                for (int j = 0; j < 8; ++j) acc[i][j] += xv[i] * wv[j];
        }
        __syncthreads();
    }

#pragma unroll
    for (int i = 0; i < 4; ++i) {
        int gr = row0 + ty * 4 + i;
        if (gr >= N_NODES) break;
        float* orow = S + (size_t)gr * OUT_DIM;
        reinterpret_cast<float4*>(orow)[tx]      = make_float4(acc[i][0], acc[i][1], acc[i][2], acc[i][3]);
        reinterpret_cast<float4*>(orow + 64)[tx] = make_float4(acc[i][4], acc[i][5], acc[i][6], acc[i][7]);
    }
}

// ---------------- CSR build ----------------
__global__ __launch_bounds__(256) void zero_cnt_kernel(int* __restrict__ cnt) {
    int i = blockIdx.x * 256 + threadIdx.x;
    if (i < N_NODES) cnt[i] = 0;
}

__global__ __launch_bounds__(256) void hist_kernel(const int* __restrict__ rows,
                                                   int* __restrict__ cnt) {
    int e = blockIdx.x * 256 + threadIdx.x;
    if (e < N_EDGES) atomicAdd(&cnt[rows[e]], 1);
}

// block-local exclusive scan of cnt (1024 elems/block) -> rstart, block sums -> bsums
__global__ __launch_bounds__(256) void scan1_kernel(const int* __restrict__ cnt,
                                                    int* __restrict__ rstart,
                                                    int* __restrict__ bsums) {
    __shared__ int tsum[256];
    const int t    = threadIdx.x;
    const int base = blockIdx.x * SCAN_BS + t * 4;
    int v[4];
#pragma unroll
    for (int j = 0; j < 4; ++j) {
        int idx = base + j;
        v[j] = (idx < N_NODES) ? cnt[idx] : 0;
    }
    tsum[t] = v[0] + v[1] + v[2] + v[3];
    __syncthreads();
    for (int off = 1; off < 256; off <<= 1) {
        int x = (t >= off) ? tsum[t - off] : 0;
        __syncthreads();
        tsum[t] += x;
        __syncthreads();
    }
    int run = (t == 0) ? 0 : tsum[t - 1];
#pragma unroll
    for (int j = 0; j < 4; ++j) {
        int idx = base + j;
        if (idx < N_NODES) rstart[idx] = run;
        run += v[j];
    }
    if (t == 255) bsums[blockIdx.x] = tsum[255];
}

__global__ void scan2_kernel(int* __restrict__ bsums) {
    if (threadIdx.x == 0 && blockIdx.x == 0) {
        int run = 0;
        for (int i = 0; i < SCAN_NB; ++i) { int v = bsums[i]; bsums[i] = run; run += v; }
    }
}

__global__ __launch_bounds__(256) void scan3_kernel(int* __restrict__ rstart,
                                                    const int* __restrict__ bsums,
                                                    int* __restrict__ rcur) {
    int i = blockIdx.x * 256 + threadIdx.x;
    if (i < N_NODES) {
        int v = rstart[i] + bsums[i / SCAN_BS];
        rstart[i] = v;
        rcur[i]   = v;
    }
    if (i == 0) rstart[N_NODES] = N_EDGES;
}

__global__ __launch_bounds__(256) void scatter_kernel(const int* __restrict__ rows,
                                                      const int* __restrict__ cols,
                                                      const float* __restrict__ vals,
                                                      int* __restrict__ rcur,
                                                      int* __restrict__ scols,
                                                      float* __restrict__ svals) {
    int e = blockIdx.x * 256 + threadIdx.x;
    if (e >= N_EDGES) return;
    int r   = rows[e];
    int pos = atomicAdd(&rcur[r], 1);
    scols[pos] = cols[e];
    svals[pos] = vals[e];
}

// ---------------- row-sum: one wave per row, float2 per lane ----------------
__global__ __launch_bounds__(256) void rowsum_kernel(const int* __restrict__ rstart,
                                                     const int* __restrict__ scols,
                                                     const float* __restrict__ svals,
                                                     const float* __restrict__ support,
                                                     const float* __restrict__ bias,
                                                     float* __restrict__ out) {
    const int wid  = (blockIdx.x * 256 + threadIdx.x) >> 6;   // row id
    const int lane = threadIdx.x & 63;
    if (wid >= N_NODES) return;

    const int beg = rstart[wid];
    const int end = rstart[wid + 1];

    float2 acc0 = make_float2(0.f, 0.f);
    float2 acc1 = make_float2(0.f, 0.f);

    int i = beg;
    for (; i + 2 <= end; i += 2) {
        int   c0 = scols[i],  c1 = scols[i + 1];
        float v0 = svals[i],  v1 = svals[i + 1];
        float2 s0 = reinterpret_cast<const float2*>(support + (size_t)c0 * OUT_DIM)[lane];
        float2 s1 = reinterpret_cast<const float2*>(support + (size_t)c1 * OUT_DIM)[lane];
        acc0.x += v0 * s0.x; acc0.y += v0 * s0.y;
        acc1.x += v1 * s1.x; acc1.y += v1 * s1.y;
    }
    if (i < end) {
        int   c0 = scols[i];
        float v0 = svals[i];
        float2 s0 = reinterpret_cast<const float2*>(support + (size_t)c0 * OUT_DIM)[lane];
        acc0.x += v0 * s0.x; acc0.y += v0 * s0.y;
    }

    float2 b = reinterpret_cast<const float2*>(bias)[lane];
    float2 r = make_float2(acc0.x + acc1.x + b.x, acc0.y + acc1.y + b.y);
    reinterpret_cast<float2*>(out + (size_t)wid * OUT_DIM)[lane] = r;
}

extern "C" void kernel_launch(void* const* d_in, const int* in_sizes, int n_in,
                              void* d_out, int out_size, void* d_ws, size_t ws_size,
                              hipStream_t stream) {
    const float* X    = (const float*)d_in[0];
    const float* W    = (const float*)d_in[1];
    const float* bias = (const float*)d_in[2];
    const int*   rows = (const int*)d_in[3];
    const int*   cols = (const int*)d_in[4];
    const float* vals = (const float*)d_in[5];
    float* out = (float*)d_out;

    // workspace layout
    float* support = (float*)d_ws;                       // 12.8M floats = 51.2 MB
    int*   scols   = (int*)(support + (size_t)N_NODES * OUT_DIM);  // 3.2M ints
    float* svals   = (float*)(scols + N_EDGES);          // 3.2M floats
    int*   rstart  = (int*)(svals + N_EDGES);            // 100001 ints
    int*   rcur    = rstart + 100032;                    // 100000 ints
    int*   bsums   = rcur + 100032;                      // 98 ints

    // 1) support = X @ W
    hipLaunchKernelGGL(gemm_kernel, dim3((N_NODES + BM - 1) / BM), dim3(256), 0, stream,
                       X, W, support);

    // 2) CSR build: zero -> hist -> scan -> scatter
    hipLaunchKernelGGL(zero_cnt_kernel, dim3((N_NODES + 255) / 256), dim3(256), 0, stream, rcur);
    hipLaunchKernelGGL(hist_kernel, dim3((N_EDGES + 255) / 256), dim3(256), 0, stream, rows, rcur);
    hipLaunchKernelGGL(scan1_kernel, dim3(SCAN_NB), dim3(256), 0, stream, rcur, rstart, bsums);
    hipLaunchKernelGGL(scan2_kernel, dim3(1), dim3(64), 0, stream, bsums);
    hipLaunchKernelGGL(scan3_kernel, dim3((N_NODES + 255) / 256), dim3(256), 0, stream,
                       rstart, bsums, rcur);
    hipLaunchKernelGGL(scatter_kernel, dim3((N_EDGES + 255) / 256), dim3(256), 0, stream,
                       rows, cols, vals, rcur, scols, svals);

    // 3) rowsum: one wave per row (4 waves/block)
    hipLaunchKernelGGL(rowsum_kernel, dim3((N_NODES + 3) / 4), dim3(256), 0, stream,
                       rstart, scols, svals, support, bias, out);
}